// Round 4
// baseline (342.714 us; speedup 1.0000x reference)
//
#include <hip/hip_runtime.h>

#define NPTS 8192
#define KNNK 16
#define NSLOT 17          // keep 17, fp64-refine drops the worst -> robust 16-set
#define LEAKY 0.1f

typedef short bf16x8 __attribute__((ext_vector_type(8)));
typedef float f32x4  __attribute__((ext_vector_type(4)));
typedef float f32x2  __attribute__((ext_vector_type(2)));

// ---- knn config ----
#define KTH   1024             // threads/block (16 waves): 16 waves/CU, 1 blk/CU
#define QPB   128              // queries per block -> grid 256
#define CHN   32               // chunks (threads) per query
#define GQ    4                // queries per thread
#define JP    (NPTS / 64)      // 128 iters, 2 adjacent candidates per thread/iter
#define BUFCAP 48              // survivor buffer per query

// ---------------------------------------------------------------------------
// R8: VALU-issue cut via packed fp32. R7 proved the kernel is VALU-bound
// (VALUBusy 74%, occupancy at its 16-wave/CU structural cap). CDNA4 VOP3P
// v_pk_fma_f32/v_pk_mul_f32 do 2xf32 per lane per inst; the loop already
// processes 2 adjacent candidates with shared per-query coefficients, so
// candidate-norm and distance chains pack exactly (hipcc won't auto-pack ->
// inline asm on ext_vector(2)). min-2 tracking uses v_med3_f32
// (m2 = med3(d,m1,m2), valid since m1<=m2). Hot-loop insts x0.59.
// Distance values bit-identical fp32; threshold/survivor/fp64-refine
// machinery unchanged from R7.
// ---------------------------------------------------------------------------

__device__ __forceinline__ f32x2 pk_fma(f32x2 a, f32x2 b, f32x2 c) {
    f32x2 d;
    asm("v_pk_fma_f32 %0, %1, %2, %3" : "=v"(d) : "v"(a), "v"(b), "v"(c));
    return d;
}

__device__ __forceinline__ f32x2 pk_mul(f32x2 a, f32x2 b) {
    f32x2 d;
    asm("v_pk_mul_f32 %0, %1, %2" : "=v"(d) : "v"(a), "v"(b));
    return d;
}

__global__ __launch_bounds__(KTH, 4) void knn_kernel(
    const float* __restrict__ pc1, const float* __restrict__ pc2,
    int* __restrict__ knn_out)
{
    __shared__ float sx[NPTS], sy[NPTS], sz[NPTS];   // 96 KB candidate SoA
    // per-query row of 96 floats: [0..47] survd, [48..95] survi (as int).
    // cols [0..63] double as the rank table before phase 2 (wave-local).
    __shared__ float sbuf[QPB][2 * BUFCAP];          // 48 KB
    __shared__ float sthr[QPB];
    __shared__ int   scnt[QPB];

    const int t   = threadIdx.x;
    const int q0  = blockIdx.x * QPB;
    const int dir = q0 >> 14;
    const int b   = (q0 >> 13) & 1;

    const float* __restrict__ pq    = dir ? pc2 : pc1;
    const float* __restrict__ pcand = dir ? pc1 : pc2;

    const float* src = pcand + (size_t)b * NPTS * 3;
    for (int i = t; i < NPTS; i += KTH) {
        sx[i] = src[3 * i];
        sy[i] = src[3 * i + 1];
        sz[i] = src[3 * i + 2];
    }
    if (t < QPB) scnt[t] = 0;
    __syncthreads();

    const int ch = t & (CHN - 1);      // chunk 0..31
    const int qg = t >> 5;             // query group 0..31 (4 queries each)
    const int n0 = q0 & (NPTS - 1);

    // q2 = -2*q, duplicated into both packed halves; |q|^2 dropped (constant
    // per query, ordering preserved).
    f32x2 q2x[GQ], q2y[GQ], q2z[GQ];
    #pragma unroll
    for (int g = 0; g < GQ; ++g) {
        const float* qp = pq + ((size_t)b * NPTS + n0 + qg * GQ + g) * 3;
        const float vx = -2.0f * qp[0];
        const float vy = -2.0f * qp[1];
        const float vz = -2.0f * qp[2];
        q2x[g][0] = vx; q2x[g][1] = vx;
        q2y[g][0] = vy; q2y[g][1] = vy;
        q2z[g][0] = vz; q2z[g][1] = vz;
    }

    // ---- phase 1: min-2 per (thread,query), branchless, packed fp32 --------
    float m1[GQ], m2[GQ];
    #pragma unroll
    for (int g = 0; g < GQ; ++g) { m1[g] = 3.0e38f; m2[g] = 3.0e38f; }

    #pragma unroll 2
    for (int j = 0; j < JP; ++j) {
        const int i0 = j * 64 + 2 * ch;
        const f32x2 cx = *(const f32x2*)&sx[i0];
        const f32x2 cy = *(const f32x2*)&sy[i0];
        const f32x2 cz = *(const f32x2*)&sz[i0];
        f32x2 cn = pk_mul(cz, cz);
        cn = pk_fma(cy, cy, cn);
        cn = pk_fma(cx, cx, cn);                     // |c|^2, both candidates
        #pragma unroll
        for (int g = 0; g < GQ; ++g) {
            f32x2 d = pk_fma(q2z[g], cz, cn);
            d = pk_fma(q2y[g], cy, d);
            d = pk_fma(q2x[g], cx, d);
            m2[g] = __builtin_amdgcn_fmed3f(d[0], m1[g], m2[g]);
            m1[g] = fminf(m1[g], d[0]);
            m2[g] = __builtin_amdgcn_fmed3f(d[1], m1[g], m2[g]);
            m1[g] = fminf(m1[g], d[1]);
        }
    }

    // ---- threshold: 17th-smallest of 64 collected, lt/eq count table ------
    #pragma unroll
    for (int g = 0; g < GQ; ++g) {
        const int row = qg * GQ + g;
        sbuf[row][2 * ch]     = m1[g];
        sbuf[row][2 * ch + 1] = m2[g];
    }
    __builtin_amdgcn_wave_barrier();   // table rows are wave-local (32-thr group)

    #pragma unroll
    for (int g = 0; g < GQ; ++g) {
        const int row = qg * GQ + g;
        const float v1 = m1[g], v2 = m2[g];
        int lt1 = 0, eq1 = 0, lt2 = 0, eq2 = 0;
        #pragma unroll
        for (int c = 0; c < 2 * CHN; c += 2) {
            const f32x2 vp = *(const f32x2*)&sbuf[row][c];
            lt1 += (vp[0] < v1) ? 1 : 0;  eq1 += (vp[0] == v1) ? 1 : 0;
            lt1 += (vp[1] < v1) ? 1 : 0;  eq1 += (vp[1] == v1) ? 1 : 0;
            lt2 += (vp[0] < v2) ? 1 : 0;  eq2 += (vp[0] == v2) ? 1 : 0;
            lt2 += (vp[1] < v2) ? 1 : 0;  eq2 += (vp[1] == v2) ? 1 : 0;
        }
        // value of rank 16 (0-based): lt <= 16 < lt+eq. Multiple writers
        // (ties) all write identical bits — benign.
        if (lt1 <= 16 && lt1 + eq1 > 16) sthr[row] = v1;
        if (lt2 <= 16 && lt2 + eq2 > 16) sthr[row] = v2;
    }
    __builtin_amdgcn_wave_barrier();

    // ---- phase 2: collect survivors (identical packed d' arithmetic) -------
    float tq[GQ];
    #pragma unroll
    for (int g = 0; g < GQ; ++g) tq[g] = sthr[qg * GQ + g];

    #pragma unroll 2
    for (int j = 0; j < JP; ++j) {
        const int i0 = j * 64 + 2 * ch;
        const f32x2 cx = *(const f32x2*)&sx[i0];
        const f32x2 cy = *(const f32x2*)&sy[i0];
        const f32x2 cz = *(const f32x2*)&sz[i0];
        f32x2 cn = pk_mul(cz, cz);
        cn = pk_fma(cy, cy, cn);
        cn = pk_fma(cx, cx, cn);
        #pragma unroll
        for (int g = 0; g < GQ; ++g) {
            f32x2 d = pk_fma(q2z[g], cz, cn);
            d = pk_fma(q2y[g], cy, d);
            d = pk_fma(q2x[g], cx, d);
            if (d[0] <= tq[g]) {
                const int q = qg * GQ + g;
                const int pos = atomicAdd(&scnt[q], 1);
                if (pos < BUFCAP) {
                    sbuf[q][pos] = d[0];
                    ((int*)&sbuf[q][BUFCAP])[pos] = i0;
                }
            }
            if (d[1] <= tq[g]) {
                const int q = qg * GQ + g;
                const int pos = atomicAdd(&scnt[q], 1);
                if (pos < BUFCAP) {
                    sbuf[q][pos] = d[1];
                    ((int*)&sbuf[q][BUFCAP])[pos] = i0 + 1;
                }
            }
        }
    }
    __syncthreads();

    // ---- phase 3: exact top-17 of survivors + fp64 refine ------------------
    if (t < QPB) {
        const int nc = min(scnt[t], BUFCAP);

        float dist[NSLOT];   // sorted descending by (d, idx); dist[0] = worst
        int   ind[NSLOT];
        #pragma unroll
        for (int i = 0; i < NSLOT; ++i) { dist[i] = 3.0e38f; ind[i] = 0x7fffffff; }

        for (int s = 0; s < nc; ++s) {
            const float d  = sbuf[t][s];
            const int   id = ((int*)&sbuf[t][BUFCAP])[s];
            const bool better0 = (d < dist[0]) || (d == dist[0] && id < ind[0]);
            if (better0) {
                bool cprev = true;
                #pragma unroll
                for (int i = 0; i < NSLOT - 1; ++i) {
                    const bool ci = (d < dist[i + 1]) ||
                                    (d == dist[i + 1] && id < ind[i + 1]);
                    const float nv = ci ? dist[i + 1] : (cprev ? d  : dist[i]);
                    const int   ni = ci ? ind[i + 1]  : (cprev ? id : ind[i]);
                    dist[i] = nv; ind[i] = ni;
                    cprev = ci;
                }
                if (cprev) { dist[NSLOT - 1] = d; ind[NSLOT - 1] = id; }
            }
        }

        const float* qpp = pq + ((size_t)b * NPTS + n0 + t) * 3;
        const double dqx = (double)qpp[0], dqy = (double)qpp[1], dqz = (double)qpp[2];
        double dd[NSLOT];
        #pragma unroll
        for (int i = 0; i < NSLOT; ++i) {
            const int id = ind[i];
            const double dx = (double)sx[id] - dqx;
            const double dy = (double)sy[id] - dqy;
            const double dz = (double)sz[id] - dqz;
            dd[i] = dx * dx + dy * dy + dz * dz;
        }
        int worst = 0; double wd = dd[0];
        #pragma unroll
        for (int i = 1; i < NSLOT; ++i) { if (dd[i] > wd) { wd = dd[i]; worst = i; } }

        int* outp = knn_out + (size_t)(q0 + t) * KNNK;
        int slot = 0;
        #pragma unroll
        for (int i = 0; i < NSLOT; ++i) {
            if (i != worst) outp[slot++] = ind[i];
        }
    }
}

// ---------------------------------------------------------------------------
// Kernel 2: feature MLP via bf16x3-split MFMA.
// Block = 256 thr (4 waves) x FP=4 points. Wave w owns N-tile w (out-channels
// 16w..16w+15); its B-fragments (hi+lo, both layers) live in registers.
// Activations pass between layers as LDS u32 = (bf16hi<<16 | bf16lo),
// row stride 68 (2-way bank aliasing only = free).
// ---------------------------------------------------------------------------
#define FP 4

__device__ __forceinline__ unsigned int packhl(float f) {
    const unsigned int u = __float_as_uint(f);
    const unsigned int h = u & 0xffff0000u;
    const float lf = f - __uint_as_float(h);
    return h | (__float_as_uint(lf) >> 16);
}

__device__ __forceinline__ void build_b(const float* __restrict__ wrow,
                                        bf16x8* hi, bf16x8* lo) {
    union { unsigned int u[4]; bf16x8 v; } H, L;
    #pragma unroll
    for (int r = 0; r < 4; ++r) {
        const float f0 = wrow[2 * r], f1 = wrow[2 * r + 1];
        const unsigned int h0 = __float_as_uint(f0) & 0xffff0000u;
        const unsigned int h1 = __float_as_uint(f1) & 0xffff0000u;
        const float l0 = f0 - __uint_as_float(h0);
        const float l1 = f1 - __uint_as_float(h1);
        H.u[r] = h1 | (h0 >> 16);
        L.u[r] = (__float_as_uint(l1) & 0xffff0000u) | (__float_as_uint(l0) >> 16);
    }
    *hi = H.v; *lo = L.v;
}

__device__ __forceinline__ void unpack_a(const unsigned int* __restrict__ Tu,
                                         bf16x8* hi, bf16x8* lo) {
    union { unsigned int u[4]; bf16x8 v; } H, L;
    #pragma unroll
    for (int r = 0; r < 4; ++r) {
        const unsigned int a = Tu[2 * r + 1], bb = Tu[2 * r];
        H.u[r] = __builtin_amdgcn_perm(a, bb, 0x07060302u);  // [a.hi16 : b.hi16]
        L.u[r] = __builtin_amdgcn_perm(a, bb, 0x05040100u);  // [a.lo16 : b.lo16]
    }
    *hi = H.v; *lo = L.v;
}

__device__ __forceinline__ f32x4 mfma3(f32x4 acc, bf16x8 ah, bf16x8 al,
                                       bf16x8 bh, bf16x8 bl) {
    acc = __builtin_amdgcn_mfma_f32_16x16x32_bf16(ah, bl, acc, 0, 0, 0);
    acc = __builtin_amdgcn_mfma_f32_16x16x32_bf16(al, bh, acc, 0, 0, 0);
    acc = __builtin_amdgcn_mfma_f32_16x16x32_bf16(ah, bh, acc, 0, 0, 0);
    return acc;
}

__global__ __launch_bounds__(256, 4) void feat_kernel(
    const float* __restrict__ pc1, const float* __restrict__ pc2,
    const float* __restrict__ feat1, const float* __restrict__ feat2,
    const float* __restrict__ pos_w, const float* __restrict__ pos_b,
    const float* __restrict__ w0, const float* __restrict__ b0,
    const float* __restrict__ w1, const float* __restrict__ b1,
    const float* __restrict__ t1w, const float* __restrict__ t1b,
    const float* __restrict__ t2w, const float* __restrict__ t2b,
    const int* __restrict__ knn, float* __restrict__ out)
{
    __shared__ unsigned int T0[FP][16][68];   // 17.4 KB packed activations
    __shared__ unsigned int T1[FP][16][68];   // 17.4 KB
    __shared__ float sm[FP][64];              // 1 KB pooled features

    const int t    = threadIdx.x;
    const int w    = t >> 6;          // wave = N-tile index 0..3
    const int lane = t & 63;
    const int m    = lane & 15;       // A-row (neighbor) / C-col (channel)
    const int quad = lane >> 4;

    const int p0  = blockIdx.x * FP;
    const int dir = p0 >> 14, bt = (p0 >> 13) & 1;
    const int n0  = p0 & (NPTS - 1);

    const float* __restrict__ pqd = dir ? pc2 : pc1;
    const float* __restrict__ pcd = dir ? pc1 : pc2;
    const float* __restrict__ fqd = dir ? feat2 : feat1;
    const float* __restrict__ fcd = dir ? feat1 : feat2;

    // ---- register-resident B-fragments: B[k][n] = W[n_glob][k] -------------
    const int ocol = w * 16 + m;               // this lane's output channel
    bf16x8 Bh[2][2], Bl[2][2];                 // [layer][ktile]
    #pragma unroll
    for (int kt = 0; kt < 2; ++kt) {
        build_b(&w0[(size_t)ocol * 64 + kt * 32 + quad * 8], &Bh[0][kt], &Bl[0][kt]);
        build_b(&w1[(size_t)ocol * 64 + kt * 32 + quad * 8], &Bh[1][kt], &Bl[1][kt]);
    }
    const float bias1 = b0[ocol];
    const float bias2 = b1[ocol];

    // ---- init-stage per-lane constants: channels cg0..cg0+3 ----------------
    const int cg0 = w * 16 + quad * 4;
    float pbc[4], pwx[4], pwy[4], pwz[4];
    #pragma unroll
    for (int i = 0; i < 4; ++i) {
        pbc[i] = pos_b[cg0 + i];
        pwx[i] = pos_w[(cg0 + i) * 3 + 0];
        pwy[i] = pos_w[(cg0 + i) * 3 + 1];
        pwz[i] = pos_w[(cg0 + i) * 3 + 2];
    }

    // ---- stage A: initial layer -> T0 (packed) -----------------------------
    #pragma unroll
    for (int pt = 0; pt < FP; ++pt) {
        const int p = p0 + pt, n = n0 + pt;
        const int id = knn[(size_t)p * KNNK + m];
        const float* qp  = pqd + ((size_t)bt * NPTS + n) * 3;
        const float* nbp = pcd + ((size_t)bt * NPTS + id) * 3;
        const float dx = nbp[0] - qp[0];
        const float dy = nbp[1] - qp[1];
        const float dz = nbp[2] - qp[2];
        const float4 gf = *(const float4*)&fcd[((size_t)bt * NPTS + id) * 64 + cg0];
        const float4 fq = *(const float4*)&fqd[((size_t)bt * NPTS + n) * 64 + cg0];
        const float gfa[4] = {gf.x, gf.y, gf.z, gf.w};
        const float fqa[4] = {fq.x, fq.y, fq.z, fq.w};
        uint4 U;
        unsigned int* Up = (unsigned int*)&U;
        #pragma unroll
        for (int i = 0; i < 4; ++i) {
            float v = gfa[i] + fqa[i] + pbc[i];
            v = fmaf(dx, pwx[i], v);
            v = fmaf(dy, pwy[i], v);
            v = fmaf(dz, pwz[i], v);
            v = fmaxf(v, LEAKY * v);
            Up[i] = packhl(v);
        }
        *(uint4*)&T0[pt][m][cg0] = U;
    }
    __syncthreads();

    // ---- stage B: layer 1 (MFMA) -> T1 -------------------------------------
    #pragma unroll
    for (int pt = 0; pt < FP; ++pt) {
        unsigned int Tu[8];
        bf16x8 Ah, Al;
        f32x4 acc = {0.f, 0.f, 0.f, 0.f};
        #pragma unroll
        for (int kt = 0; kt < 2; ++kt) {
            *(uint4*)&Tu[0] = *(const uint4*)&T0[pt][m][kt * 32 + quad * 8];
            *(uint4*)&Tu[4] = *(const uint4*)&T0[pt][m][kt * 32 + quad * 8 + 4];
            unpack_a(Tu, &Ah, &Al);
            acc = mfma3(acc, Ah, Al, Bh[0][kt], Bl[0][kt]);
        }
        #pragma unroll
        for (int r = 0; r < 4; ++r) {
            float v = acc[r] + bias1;
            v = fmaxf(v, LEAKY * v);
            T1[pt][quad * 4 + r][ocol] = packhl(v);
        }
    }
    __syncthreads();

    // ---- stage C: layer 2 (MFMA) + max-pool -> sm --------------------------
    #pragma unroll
    for (int pt = 0; pt < FP; ++pt) {
        unsigned int Tu[8];
        bf16x8 Ah, Al;
        f32x4 acc = {0.f, 0.f, 0.f, 0.f};
        #pragma unroll
        for (int kt = 0; kt < 2; ++kt) {
            *(uint4*)&Tu[0] = *(const uint4*)&T1[pt][m][kt * 32 + quad * 8];
            *(uint4*)&Tu[4] = *(const uint4*)&T1[pt][m][kt * 32 + quad * 8 + 4];
            unpack_a(Tu, &Ah, &Al);
            acc = mfma3(acc, Ah, Al, Bh[1][kt], Bl[1][kt]);
        }
        float mx = -3.0e38f;
        #pragma unroll
        for (int r = 0; r < 4; ++r) {
            float v = acc[r] + bias2;
            v = fmaxf(v, LEAKY * v);
            mx = fmaxf(mx, v);
        }
        mx = fmaxf(mx, __shfl_xor(mx, 16));
        mx = fmaxf(mx, __shfl_xor(mx, 32));
        if (quad == 0) sm[pt][ocol] = mx;
    }
    __syncthreads();

    // ---- stage D: final 64->128 linear -------------------------------------
    {
        const float* __restrict__ tw = dir ? t2w : t1w;
        const float* __restrict__ tb = dir ? t2b : t1b;
        const int o  = t & 127;
        const int pg = t >> 7;                 // 2 point-pairs
        const int pa = pg * 2, pb = pg * 2 + 1;
        float acc0 = tb[o], acc1 = acc0;
        #pragma unroll
        for (int cc = 0; cc < 64; cc += 4) {
            const float4 wq = *(const float4*)&tw[(size_t)o * 64 + cc];
            const float4 a0 = *(const float4*)&sm[pa][cc];
            const float4 a1 = *(const float4*)&sm[pb][cc];
            acc0 = fmaf(a0.x, wq.x, acc0); acc0 = fmaf(a0.y, wq.y, acc0);
            acc0 = fmaf(a0.z, wq.z, acc0); acc0 = fmaf(a0.w, wq.w, acc0);
            acc1 = fmaf(a1.x, wq.x, acc1); acc1 = fmaf(a1.y, wq.y, acc1);
            acc1 = fmaf(a1.z, wq.z, acc1); acc1 = fmaf(a1.w, wq.w, acc1);
        }
        float* op = out + (size_t)dir * (2 * NPTS * 128);
        op[((size_t)bt * NPTS + n0 + pa) * 128 + o] = acc0;
        op[((size_t)bt * NPTS + n0 + pb) * 128 + o] = acc1;
    }
}

// ---------------------------------------------------------------------------
extern "C" void kernel_launch(void* const* d_in, const int* in_sizes, int n_in,
                              void* d_out, int out_size, void* d_ws, size_t ws_size,
                              hipStream_t stream)
{
    const float* pc1   = (const float*)d_in[0];
    const float* pc2   = (const float*)d_in[1];
    const float* feat1 = (const float*)d_in[2];
    const float* feat2 = (const float*)d_in[3];
    const float* pos_w = (const float*)d_in[4];
    const float* pos_b = (const float*)d_in[5];
    const float* w0    = (const float*)d_in[6];
    const float* b0    = (const float*)d_in[7];
    const float* w1    = (const float*)d_in[8];
    const float* b1    = (const float*)d_in[9];
    const float* t1w   = (const float*)d_in[10];
    const float* t1b   = (const float*)d_in[11];
    const float* t2w   = (const float*)d_in[12];
    const float* t2b   = (const float*)d_in[13];

    int*   knn = (int*)d_ws;          // 32768 * 16 ints = 2 MB scratch
    float* out = (float*)d_out;

    hipLaunchKernelGGL(knn_kernel, dim3(32768 / QPB), dim3(KTH), 0, stream,
                       pc1, pc2, knn);
    hipLaunchKernelGGL(feat_kernel, dim3(32768 / FP), dim3(256), 0, stream,
                       pc1, pc2, feat1, feat2, pos_w, pos_b,
                       w0, b0, w1, b1, t1w, t1b, t2w, t2b, knn, out);
}

// Round 5
// 321.568 us; speedup vs baseline: 1.0658x; 1.0658x over previous
//
#include <hip/hip_runtime.h>

#define NPTS 8192
#define KNNK 16
#define NSLOT 17          // keep 17, fp64-refine drops the worst -> robust 16-set
#define LEAKY 0.1f

typedef short bf16x8 __attribute__((ext_vector_type(8)));
typedef float f32x4  __attribute__((ext_vector_type(4)));

// ---- knn config ----
#define KTH   1024             // threads/block (16 waves): 16 waves/CU, 1 blk/CU
#define QPB   128              // queries per block -> grid 256
#define CHN   32               // chunks (threads) per query
#define GQ    4                // queries per thread
#define JP4   (NPTS / (CHN * 4))   // 64 iters, 4 adjacent candidates per thread
#define BUFCAP 48              // survivor buffer per query

// ---------------------------------------------------------------------------
// R9: revert R8's packed fp32 (scalar v_fma_f32 already saturates the SIMD-32
// pipe at 2cyc/wave; v_pk_* only saves issue slots and the asm blocks broke
// scheduling -> 143->154us regression). Keep fmed3 min-2 (2 ops -> 1).
// New: 4-candidate blocking via ds_read_b128 — per 4 candidates: 3 LDS insts
// (was 6), half the loop iterations, 4 independent distance chains per iter
// (better ILP for latency hiding). Per-pair VALU unchanged, distances
// bit-identical fp32. Threshold (32-chunk min-2, 64-entry rank table),
// survivor buffer, fp64 refine all unchanged.
// ---------------------------------------------------------------------------
__global__ __launch_bounds__(KTH, 4) void knn_kernel(
    const float* __restrict__ pc1, const float* __restrict__ pc2,
    int* __restrict__ knn_out)
{
    __shared__ float sx[NPTS], sy[NPTS], sz[NPTS];   // 96 KB candidate SoA
    // per-query row of 96 floats: [0..47] survd, [48..95] survi (as int).
    // cols [0..63] double as the rank table before phase 2 (wave-local).
    __shared__ float sbuf[QPB][2 * BUFCAP];          // 48 KB
    __shared__ float sthr[QPB];
    __shared__ int   scnt[QPB];

    const int t   = threadIdx.x;
    const int q0  = blockIdx.x * QPB;
    const int dir = q0 >> 14;
    const int b   = (q0 >> 13) & 1;

    const float* __restrict__ pq    = dir ? pc2 : pc1;
    const float* __restrict__ pcand = dir ? pc1 : pc2;

    const float* src = pcand + (size_t)b * NPTS * 3;
    for (int i = t; i < NPTS; i += KTH) {
        sx[i] = src[3 * i];
        sy[i] = src[3 * i + 1];
        sz[i] = src[3 * i + 2];
    }
    if (t < QPB) scnt[t] = 0;
    __syncthreads();

    const int ch = t & (CHN - 1);      // chunk 0..31
    const int qg = t >> 5;             // query group 0..31 (4 queries each)
    const int n0 = q0 & (NPTS - 1);

    // q2 = -2*q ; |q|^2 dropped (constant per query, ordering preserved)
    float q2x[GQ], q2y[GQ], q2z[GQ];
    #pragma unroll
    for (int g = 0; g < GQ; ++g) {
        const float* qp = pq + ((size_t)b * NPTS + n0 + qg * GQ + g) * 3;
        q2x[g] = -2.0f * qp[0];
        q2y[g] = -2.0f * qp[1];
        q2z[g] = -2.0f * qp[2];
    }

    // ---- phase 1: min-2 per (thread,query), branchless ---------------------
    float m1[GQ], m2[GQ];
    #pragma unroll
    for (int g = 0; g < GQ; ++g) { m1[g] = 3.0e38f; m2[g] = 3.0e38f; }

    #pragma unroll 2
    for (int j = 0; j < JP4; ++j) {
        const int i0 = j * 128 + 4 * ch;
        const f32x4 cx = *(const f32x4*)&sx[i0];
        const f32x4 cy = *(const f32x4*)&sy[i0];
        const f32x4 cz = *(const f32x4*)&sz[i0];
        f32x4 cn;
        #pragma unroll
        for (int c = 0; c < 4; ++c)
            cn[c] = fmaf(cx[c], cx[c], fmaf(cy[c], cy[c], cz[c] * cz[c]));
        #pragma unroll
        for (int g = 0; g < GQ; ++g) {
            #pragma unroll
            for (int c = 0; c < 4; ++c) {
                const float d = fmaf(q2x[g], cx[c],
                                fmaf(q2y[g], cy[c],
                                fmaf(q2z[g], cz[c], cn[c])));
                m2[g] = __builtin_amdgcn_fmed3f(d, m1[g], m2[g]);  // keeps 2nd-min
                m1[g] = fminf(m1[g], d);
            }
        }
    }

    // ---- threshold: 17th-smallest of 64 collected, lt/eq count table ------
    #pragma unroll
    for (int g = 0; g < GQ; ++g) {
        const int row = qg * GQ + g;
        sbuf[row][2 * ch]     = m1[g];
        sbuf[row][2 * ch + 1] = m2[g];
    }
    __builtin_amdgcn_wave_barrier();   // table rows are wave-local (32-thr group)

    #pragma unroll
    for (int g = 0; g < GQ; ++g) {
        const int row = qg * GQ + g;
        const float v1 = m1[g], v2 = m2[g];
        int lt1 = 0, eq1 = 0, lt2 = 0, eq2 = 0;
        #pragma unroll
        for (int c = 0; c < 2 * CHN; c += 2) {
            const float2 vp = *(const float2*)&sbuf[row][c];
            lt1 += (vp.x < v1) ? 1 : 0;  eq1 += (vp.x == v1) ? 1 : 0;
            lt1 += (vp.y < v1) ? 1 : 0;  eq1 += (vp.y == v1) ? 1 : 0;
            lt2 += (vp.x < v2) ? 1 : 0;  eq2 += (vp.x == v2) ? 1 : 0;
            lt2 += (vp.y < v2) ? 1 : 0;  eq2 += (vp.y == v2) ? 1 : 0;
        }
        // value of rank 16 (0-based): lt <= 16 < lt+eq. Multiple writers
        // (ties) all write identical bits — benign.
        if (lt1 <= 16 && lt1 + eq1 > 16) sthr[row] = v1;
        if (lt2 <= 16 && lt2 + eq2 > 16) sthr[row] = v2;
    }
    __builtin_amdgcn_wave_barrier();

    // ---- phase 2: collect survivors (identical d' arithmetic) --------------
    float tq[GQ];
    #pragma unroll
    for (int g = 0; g < GQ; ++g) tq[g] = sthr[qg * GQ + g];

    #pragma unroll 2
    for (int j = 0; j < JP4; ++j) {
        const int i0 = j * 128 + 4 * ch;
        const f32x4 cx = *(const f32x4*)&sx[i0];
        const f32x4 cy = *(const f32x4*)&sy[i0];
        const f32x4 cz = *(const f32x4*)&sz[i0];
        f32x4 cn;
        #pragma unroll
        for (int c = 0; c < 4; ++c)
            cn[c] = fmaf(cx[c], cx[c], fmaf(cy[c], cy[c], cz[c] * cz[c]));
        #pragma unroll
        for (int g = 0; g < GQ; ++g) {
            #pragma unroll
            for (int c = 0; c < 4; ++c) {
                const float d = fmaf(q2x[g], cx[c],
                                fmaf(q2y[g], cy[c],
                                fmaf(q2z[g], cz[c], cn[c])));
                if (d <= tq[g]) {
                    const int q = qg * GQ + g;
                    const int pos = atomicAdd(&scnt[q], 1);
                    if (pos < BUFCAP) {
                        sbuf[q][pos] = d;
                        ((int*)&sbuf[q][BUFCAP])[pos] = i0 + c;
                    }
                }
            }
        }
    }
    __syncthreads();

    // ---- phase 3: exact top-17 of survivors + fp64 refine ------------------
    if (t < QPB) {
        const int nc = min(scnt[t], BUFCAP);

        float dist[NSLOT];   // sorted descending by (d, idx); dist[0] = worst
        int   ind[NSLOT];
        #pragma unroll
        for (int i = 0; i < NSLOT; ++i) { dist[i] = 3.0e38f; ind[i] = 0x7fffffff; }

        for (int s = 0; s < nc; ++s) {
            const float d  = sbuf[t][s];
            const int   id = ((int*)&sbuf[t][BUFCAP])[s];
            const bool better0 = (d < dist[0]) || (d == dist[0] && id < ind[0]);
            if (better0) {
                bool cprev = true;
                #pragma unroll
                for (int i = 0; i < NSLOT - 1; ++i) {
                    const bool ci = (d < dist[i + 1]) ||
                                    (d == dist[i + 1] && id < ind[i + 1]);
                    const float nv = ci ? dist[i + 1] : (cprev ? d  : dist[i]);
                    const int   ni = ci ? ind[i + 1]  : (cprev ? id : ind[i]);
                    dist[i] = nv; ind[i] = ni;
                    cprev = ci;
                }
                if (cprev) { dist[NSLOT - 1] = d; ind[NSLOT - 1] = id; }
            }
        }

        const float* qpp = pq + ((size_t)b * NPTS + n0 + t) * 3;
        const double dqx = (double)qpp[0], dqy = (double)qpp[1], dqz = (double)qpp[2];
        double dd[NSLOT];
        #pragma unroll
        for (int i = 0; i < NSLOT; ++i) {
            const int id = ind[i];
            const double dx = (double)sx[id] - dqx;
            const double dy = (double)sy[id] - dqy;
            const double dz = (double)sz[id] - dqz;
            dd[i] = dx * dx + dy * dy + dz * dz;
        }
        int worst = 0; double wd = dd[0];
        #pragma unroll
        for (int i = 1; i < NSLOT; ++i) { if (dd[i] > wd) { wd = dd[i]; worst = i; } }

        int* outp = knn_out + (size_t)(q0 + t) * KNNK;
        int slot = 0;
        #pragma unroll
        for (int i = 0; i < NSLOT; ++i) {
            if (i != worst) outp[slot++] = ind[i];
        }
    }
}

// ---------------------------------------------------------------------------
// Kernel 2: feature MLP via bf16x3-split MFMA.
// Block = 256 thr (4 waves) x FP=4 points. Wave w owns N-tile w (out-channels
// 16w..16w+15); its B-fragments (hi+lo, both layers) live in registers.
// Activations pass between layers as LDS u32 = (bf16hi<<16 | bf16lo),
// row stride 68 (2-way bank aliasing only = free).
// ---------------------------------------------------------------------------
#define FP 4

__device__ __forceinline__ unsigned int packhl(float f) {
    const unsigned int u = __float_as_uint(f);
    const unsigned int h = u & 0xffff0000u;
    const float lf = f - __uint_as_float(h);
    return h | (__float_as_uint(lf) >> 16);
}

__device__ __forceinline__ void build_b(const float* __restrict__ wrow,
                                        bf16x8* hi, bf16x8* lo) {
    union { unsigned int u[4]; bf16x8 v; } H, L;
    #pragma unroll
    for (int r = 0; r < 4; ++r) {
        const float f0 = wrow[2 * r], f1 = wrow[2 * r + 1];
        const unsigned int h0 = __float_as_uint(f0) & 0xffff0000u;
        const unsigned int h1 = __float_as_uint(f1) & 0xffff0000u;
        const float l0 = f0 - __uint_as_float(h0);
        const float l1 = f1 - __uint_as_float(h1);
        H.u[r] = h1 | (h0 >> 16);
        L.u[r] = (__float_as_uint(l1) & 0xffff0000u) | (__float_as_uint(l0) >> 16);
    }
    *hi = H.v; *lo = L.v;
}

__device__ __forceinline__ void unpack_a(const unsigned int* __restrict__ Tu,
                                         bf16x8* hi, bf16x8* lo) {
    union { unsigned int u[4]; bf16x8 v; } H, L;
    #pragma unroll
    for (int r = 0; r < 4; ++r) {
        const unsigned int a = Tu[2 * r + 1], bb = Tu[2 * r];
        H.u[r] = __builtin_amdgcn_perm(a, bb, 0x07060302u);  // [a.hi16 : b.hi16]
        L.u[r] = __builtin_amdgcn_perm(a, bb, 0x05040100u);  // [a.lo16 : b.lo16]
    }
    *hi = H.v; *lo = L.v;
}

__device__ __forceinline__ f32x4 mfma3(f32x4 acc, bf16x8 ah, bf16x8 al,
                                       bf16x8 bh, bf16x8 bl) {
    acc = __builtin_amdgcn_mfma_f32_16x16x32_bf16(ah, bl, acc, 0, 0, 0);
    acc = __builtin_amdgcn_mfma_f32_16x16x32_bf16(al, bh, acc, 0, 0, 0);
    acc = __builtin_amdgcn_mfma_f32_16x16x32_bf16(ah, bh, acc, 0, 0, 0);
    return acc;
}

__global__ __launch_bounds__(256, 4) void feat_kernel(
    const float* __restrict__ pc1, const float* __restrict__ pc2,
    const float* __restrict__ feat1, const float* __restrict__ feat2,
    const float* __restrict__ pos_w, const float* __restrict__ pos_b,
    const float* __restrict__ w0, const float* __restrict__ b0,
    const float* __restrict__ w1, const float* __restrict__ b1,
    const float* __restrict__ t1w, const float* __restrict__ t1b,
    const float* __restrict__ t2w, const float* __restrict__ t2b,
    const int* __restrict__ knn, float* __restrict__ out)
{
    __shared__ unsigned int T0[FP][16][68];   // 17.4 KB packed activations
    __shared__ unsigned int T1[FP][16][68];   // 17.4 KB
    __shared__ float sm[FP][64];              // 1 KB pooled features

    const int t    = threadIdx.x;
    const int w    = t >> 6;          // wave = N-tile index 0..3
    const int lane = t & 63;
    const int m    = lane & 15;       // A-row (neighbor) / C-col (channel)
    const int quad = lane >> 4;

    const int p0  = blockIdx.x * FP;
    const int dir = p0 >> 14, bt = (p0 >> 13) & 1;
    const int n0  = p0 & (NPTS - 1);

    const float* __restrict__ pqd = dir ? pc2 : pc1;
    const float* __restrict__ pcd = dir ? pc1 : pc2;
    const float* __restrict__ fqd = dir ? feat2 : feat1;
    const float* __restrict__ fcd = dir ? feat1 : feat2;

    // ---- register-resident B-fragments: B[k][n] = W[n_glob][k] -------------
    const int ocol = w * 16 + m;               // this lane's output channel
    bf16x8 Bh[2][2], Bl[2][2];                 // [layer][ktile]
    #pragma unroll
    for (int kt = 0; kt < 2; ++kt) {
        build_b(&w0[(size_t)ocol * 64 + kt * 32 + quad * 8], &Bh[0][kt], &Bl[0][kt]);
        build_b(&w1[(size_t)ocol * 64 + kt * 32 + quad * 8], &Bh[1][kt], &Bl[1][kt]);
    }
    const float bias1 = b0[ocol];
    const float bias2 = b1[ocol];

    // ---- init-stage per-lane constants: channels cg0..cg0+3 ----------------
    const int cg0 = w * 16 + quad * 4;
    float pbc[4], pwx[4], pwy[4], pwz[4];
    #pragma unroll
    for (int i = 0; i < 4; ++i) {
        pbc[i] = pos_b[cg0 + i];
        pwx[i] = pos_w[(cg0 + i) * 3 + 0];
        pwy[i] = pos_w[(cg0 + i) * 3 + 1];
        pwz[i] = pos_w[(cg0 + i) * 3 + 2];
    }

    // ---- stage A: initial layer -> T0 (packed) -----------------------------
    #pragma unroll
    for (int pt = 0; pt < FP; ++pt) {
        const int p = p0 + pt, n = n0 + pt;
        const int id = knn[(size_t)p * KNNK + m];
        const float* qp  = pqd + ((size_t)bt * NPTS + n) * 3;
        const float* nbp = pcd + ((size_t)bt * NPTS + id) * 3;
        const float dx = nbp[0] - qp[0];
        const float dy = nbp[1] - qp[1];
        const float dz = nbp[2] - qp[2];
        const float4 gf = *(const float4*)&fcd[((size_t)bt * NPTS + id) * 64 + cg0];
        const float4 fq = *(const float4*)&fqd[((size_t)bt * NPTS + n) * 64 + cg0];
        const float gfa[4] = {gf.x, gf.y, gf.z, gf.w};
        const float fqa[4] = {fq.x, fq.y, fq.z, fq.w};
        uint4 U;
        unsigned int* Up = (unsigned int*)&U;
        #pragma unroll
        for (int i = 0; i < 4; ++i) {
            float v = gfa[i] + fqa[i] + pbc[i];
            v = fmaf(dx, pwx[i], v);
            v = fmaf(dy, pwy[i], v);
            v = fmaf(dz, pwz[i], v);
            v = fmaxf(v, LEAKY * v);
            Up[i] = packhl(v);
        }
        *(uint4*)&T0[pt][m][cg0] = U;
    }
    __syncthreads();

    // ---- stage B: layer 1 (MFMA) -> T1 -------------------------------------
    #pragma unroll
    for (int pt = 0; pt < FP; ++pt) {
        unsigned int Tu[8];
        bf16x8 Ah, Al;
        f32x4 acc = {0.f, 0.f, 0.f, 0.f};
        #pragma unroll
        for (int kt = 0; kt < 2; ++kt) {
            *(uint4*)&Tu[0] = *(const uint4*)&T0[pt][m][kt * 32 + quad * 8];
            *(uint4*)&Tu[4] = *(const uint4*)&T0[pt][m][kt * 32 + quad * 8 + 4];
            unpack_a(Tu, &Ah, &Al);
            acc = mfma3(acc, Ah, Al, Bh[0][kt], Bl[0][kt]);
        }
        #pragma unroll
        for (int r = 0; r < 4; ++r) {
            float v = acc[r] + bias1;
            v = fmaxf(v, LEAKY * v);
            T1[pt][quad * 4 + r][ocol] = packhl(v);
        }
    }
    __syncthreads();

    // ---- stage C: layer 2 (MFMA) + max-pool -> sm --------------------------
    #pragma unroll
    for (int pt = 0; pt < FP; ++pt) {
        unsigned int Tu[8];
        bf16x8 Ah, Al;
        f32x4 acc = {0.f, 0.f, 0.f, 0.f};
        #pragma unroll
        for (int kt = 0; kt < 2; ++kt) {
            *(uint4*)&Tu[0] = *(const uint4*)&T1[pt][m][kt * 32 + quad * 8];
            *(uint4*)&Tu[4] = *(const uint4*)&T1[pt][m][kt * 32 + quad * 8 + 4];
            unpack_a(Tu, &Ah, &Al);
            acc = mfma3(acc, Ah, Al, Bh[1][kt], Bl[1][kt]);
        }
        float mx = -3.0e38f;
        #pragma unroll
        for (int r = 0; r < 4; ++r) {
            float v = acc[r] + bias2;
            v = fmaxf(v, LEAKY * v);
            mx = fmaxf(mx, v);
        }
        mx = fmaxf(mx, __shfl_xor(mx, 16));
        mx = fmaxf(mx, __shfl_xor(mx, 32));
        if (quad == 0) sm[pt][ocol] = mx;
    }
    __syncthreads();

    // ---- stage D: final 64->128 linear -------------------------------------
    {
        const float* __restrict__ tw = dir ? t2w : t1w;
        const float* __restrict__ tb = dir ? t2b : t1b;
        const int o  = t & 127;
        const int pg = t >> 7;                 // 2 point-pairs
        const int pa = pg * 2, pb = pg * 2 + 1;
        float acc0 = tb[o], acc1 = acc0;
        #pragma unroll
        for (int cc = 0; cc < 64; cc += 4) {
            const float4 wq = *(const float4*)&tw[(size_t)o * 64 + cc];
            const float4 a0 = *(const float4*)&sm[pa][cc];
            const float4 a1 = *(const float4*)&sm[pb][cc];
            acc0 = fmaf(a0.x, wq.x, acc0); acc0 = fmaf(a0.y, wq.y, acc0);
            acc0 = fmaf(a0.z, wq.z, acc0); acc0 = fmaf(a0.w, wq.w, acc0);
            acc1 = fmaf(a1.x, wq.x, acc1); acc1 = fmaf(a1.y, wq.y, acc1);
            acc1 = fmaf(a1.z, wq.z, acc1); acc1 = fmaf(a1.w, wq.w, acc1);
        }
        float* op = out + (size_t)dir * (2 * NPTS * 128);
        op[((size_t)bt * NPTS + n0 + pa) * 128 + o] = acc0;
        op[((size_t)bt * NPTS + n0 + pb) * 128 + o] = acc1;
    }
}

// ---------------------------------------------------------------------------
extern "C" void kernel_launch(void* const* d_in, const int* in_sizes, int n_in,
                              void* d_out, int out_size, void* d_ws, size_t ws_size,
                              hipStream_t stream)
{
    const float* pc1   = (const float*)d_in[0];
    const float* pc2   = (const float*)d_in[1];
    const float* feat1 = (const float*)d_in[2];
    const float* feat2 = (const float*)d_in[3];
    const float* pos_w = (const float*)d_in[4];
    const float* pos_b = (const float*)d_in[5];
    const float* w0    = (const float*)d_in[6];
    const float* b0    = (const float*)d_in[7];
    const float* w1    = (const float*)d_in[8];
    const float* b1    = (const float*)d_in[9];
    const float* t1w   = (const float*)d_in[10];
    const float* t1b   = (const float*)d_in[11];
    const float* t2w   = (const float*)d_in[12];
    const float* t2b   = (const float*)d_in[13];

    int*   knn = (int*)d_ws;          // 32768 * 16 ints = 2 MB scratch
    float* out = (float*)d_out;

    hipLaunchKernelGGL(knn_kernel, dim3(32768 / QPB), dim3(KTH), 0, stream,
                       pc1, pc2, knn);
    hipLaunchKernelGGL(feat_kernel, dim3(32768 / FP), dim3(256), 0, stream,
                       pc1, pc2, feat1, feat2, pos_w, pos_b,
                       w0, b0, w1, b1, t1w, t1b, t2w, t2b, knn, out);
}

// Round 6
// 272.874 us; speedup vs baseline: 1.2559x; 1.1784x over previous
//
#include <hip/hip_runtime.h>

#define NPTS 8192
#define KNNK 16
#define NSLOT 17          // keep 17, fp64-refine drops the worst -> robust 16-set
#define LEAKY 0.1f

typedef short bf16x8 __attribute__((ext_vector_type(8)));
typedef float f32x4  __attribute__((ext_vector_type(4)));

// ---- knn config ----
#define KTH   1024             // threads/block (16 waves): 16 waves/CU, 1 blk/CU
#define QPB   128              // queries per block -> grid 256
#define CHN   32               // chunks (threads) per query
#define GQ    4                // queries per thread
#define JP4   (NPTS / (CHN * 4))   // 64 iters, 4 adjacent candidates per thread
#define BUFCAP 48              // survivor buffer per query

// ---------------------------------------------------------------------------
// knn_kernel: unchanged from R9 (ds_read_b128 4-candidate blocking + fmed3
// min-2 + rank-17 threshold + survivor buffer + fp64 refine). R9 dropped it
// below feat_kernel (<132us).
// ---------------------------------------------------------------------------
__global__ __launch_bounds__(KTH, 4) void knn_kernel(
    const float* __restrict__ pc1, const float* __restrict__ pc2,
    int* __restrict__ knn_out)
{
    __shared__ float sx[NPTS], sy[NPTS], sz[NPTS];   // 96 KB candidate SoA
    __shared__ float sbuf[QPB][2 * BUFCAP];          // 48 KB
    __shared__ float sthr[QPB];
    __shared__ int   scnt[QPB];

    const int t   = threadIdx.x;
    const int q0  = blockIdx.x * QPB;
    const int dir = q0 >> 14;
    const int b   = (q0 >> 13) & 1;

    const float* __restrict__ pq    = dir ? pc2 : pc1;
    const float* __restrict__ pcand = dir ? pc1 : pc2;

    const float* src = pcand + (size_t)b * NPTS * 3;
    for (int i = t; i < NPTS; i += KTH) {
        sx[i] = src[3 * i];
        sy[i] = src[3 * i + 1];
        sz[i] = src[3 * i + 2];
    }
    if (t < QPB) scnt[t] = 0;
    __syncthreads();

    const int ch = t & (CHN - 1);      // chunk 0..31
    const int qg = t >> 5;             // query group 0..31 (4 queries each)
    const int n0 = q0 & (NPTS - 1);

    // q2 = -2*q ; |q|^2 dropped (constant per query, ordering preserved)
    float q2x[GQ], q2y[GQ], q2z[GQ];
    #pragma unroll
    for (int g = 0; g < GQ; ++g) {
        const float* qp = pq + ((size_t)b * NPTS + n0 + qg * GQ + g) * 3;
        q2x[g] = -2.0f * qp[0];
        q2y[g] = -2.0f * qp[1];
        q2z[g] = -2.0f * qp[2];
    }

    // ---- phase 1: min-2 per (thread,query), branchless ---------------------
    float m1[GQ], m2[GQ];
    #pragma unroll
    for (int g = 0; g < GQ; ++g) { m1[g] = 3.0e38f; m2[g] = 3.0e38f; }

    #pragma unroll 2
    for (int j = 0; j < JP4; ++j) {
        const int i0 = j * 128 + 4 * ch;
        const f32x4 cx = *(const f32x4*)&sx[i0];
        const f32x4 cy = *(const f32x4*)&sy[i0];
        const f32x4 cz = *(const f32x4*)&sz[i0];
        f32x4 cn;
        #pragma unroll
        for (int c = 0; c < 4; ++c)
            cn[c] = fmaf(cx[c], cx[c], fmaf(cy[c], cy[c], cz[c] * cz[c]));
        #pragma unroll
        for (int g = 0; g < GQ; ++g) {
            #pragma unroll
            for (int c = 0; c < 4; ++c) {
                const float d = fmaf(q2x[g], cx[c],
                                fmaf(q2y[g], cy[c],
                                fmaf(q2z[g], cz[c], cn[c])));
                m2[g] = __builtin_amdgcn_fmed3f(d, m1[g], m2[g]);  // keeps 2nd-min
                m1[g] = fminf(m1[g], d);
            }
        }
    }

    // ---- threshold: 17th-smallest of 64 collected, lt/eq count table ------
    #pragma unroll
    for (int g = 0; g < GQ; ++g) {
        const int row = qg * GQ + g;
        sbuf[row][2 * ch]     = m1[g];
        sbuf[row][2 * ch + 1] = m2[g];
    }
    __builtin_amdgcn_wave_barrier();   // table rows are wave-local (32-thr group)

    #pragma unroll
    for (int g = 0; g < GQ; ++g) {
        const int row = qg * GQ + g;
        const float v1 = m1[g], v2 = m2[g];
        int lt1 = 0, eq1 = 0, lt2 = 0, eq2 = 0;
        #pragma unroll
        for (int c = 0; c < 2 * CHN; c += 2) {
            const float2 vp = *(const float2*)&sbuf[row][c];
            lt1 += (vp.x < v1) ? 1 : 0;  eq1 += (vp.x == v1) ? 1 : 0;
            lt1 += (vp.y < v1) ? 1 : 0;  eq1 += (vp.y == v1) ? 1 : 0;
            lt2 += (vp.x < v2) ? 1 : 0;  eq2 += (vp.x == v2) ? 1 : 0;
            lt2 += (vp.y < v2) ? 1 : 0;  eq2 += (vp.y == v2) ? 1 : 0;
        }
        // value of rank 16 (0-based): lt <= 16 < lt+eq. Ties all write
        // identical bits — benign.
        if (lt1 <= 16 && lt1 + eq1 > 16) sthr[row] = v1;
        if (lt2 <= 16 && lt2 + eq2 > 16) sthr[row] = v2;
    }
    __builtin_amdgcn_wave_barrier();

    // ---- phase 2: collect survivors (identical d' arithmetic) --------------
    float tq[GQ];
    #pragma unroll
    for (int g = 0; g < GQ; ++g) tq[g] = sthr[qg * GQ + g];

    #pragma unroll 2
    for (int j = 0; j < JP4; ++j) {
        const int i0 = j * 128 + 4 * ch;
        const f32x4 cx = *(const f32x4*)&sx[i0];
        const f32x4 cy = *(const f32x4*)&sy[i0];
        const f32x4 cz = *(const f32x4*)&sz[i0];
        f32x4 cn;
        #pragma unroll
        for (int c = 0; c < 4; ++c)
            cn[c] = fmaf(cx[c], cx[c], fmaf(cy[c], cy[c], cz[c] * cz[c]));
        #pragma unroll
        for (int g = 0; g < GQ; ++g) {
            #pragma unroll
            for (int c = 0; c < 4; ++c) {
                const float d = fmaf(q2x[g], cx[c],
                                fmaf(q2y[g], cy[c],
                                fmaf(q2z[g], cz[c], cn[c])));
                if (d <= tq[g]) {
                    const int q = qg * GQ + g;
                    const int pos = atomicAdd(&scnt[q], 1);
                    if (pos < BUFCAP) {
                        sbuf[q][pos] = d;
                        ((int*)&sbuf[q][BUFCAP])[pos] = i0 + c;
                    }
                }
            }
        }
    }
    __syncthreads();

    // ---- phase 3: exact top-17 of survivors + fp64 refine ------------------
    if (t < QPB) {
        const int nc = min(scnt[t], BUFCAP);

        float dist[NSLOT];   // sorted descending by (d, idx); dist[0] = worst
        int   ind[NSLOT];
        #pragma unroll
        for (int i = 0; i < NSLOT; ++i) { dist[i] = 3.0e38f; ind[i] = 0x7fffffff; }

        for (int s = 0; s < nc; ++s) {
            const float d  = sbuf[t][s];
            const int   id = ((int*)&sbuf[t][BUFCAP])[s];
            const bool better0 = (d < dist[0]) || (d == dist[0] && id < ind[0]);
            if (better0) {
                bool cprev = true;
                #pragma unroll
                for (int i = 0; i < NSLOT - 1; ++i) {
                    const bool ci = (d < dist[i + 1]) ||
                                    (d == dist[i + 1] && id < ind[i + 1]);
                    const float nv = ci ? dist[i + 1] : (cprev ? d  : dist[i]);
                    const int   ni = ci ? ind[i + 1]  : (cprev ? id : ind[i]);
                    dist[i] = nv; ind[i] = ni;
                    cprev = ci;
                }
                if (cprev) { dist[NSLOT - 1] = d; ind[NSLOT - 1] = id; }
            }
        }

        const float* qpp = pq + ((size_t)b * NPTS + n0 + t) * 3;
        const double dqx = (double)qpp[0], dqy = (double)qpp[1], dqz = (double)qpp[2];
        double dd[NSLOT];
        #pragma unroll
        for (int i = 0; i < NSLOT; ++i) {
            const int id = ind[i];
            const double dx = (double)sx[id] - dqx;
            const double dy = (double)sy[id] - dqy;
            const double dz = (double)sz[id] - dqz;
            dd[i] = dx * dx + dy * dy + dz * dz;
        }
        int worst = 0; double wd = dd[0];
        #pragma unroll
        for (int i = 1; i < NSLOT; ++i) { if (dd[i] > wd) { wd = dd[i]; worst = i; } }

        int* outp = knn_out + (size_t)(q0 + t) * KNNK;
        int slot = 0;
        #pragma unroll
        for (int i = 0; i < NSLOT; ++i) {
            if (i != worst) outp[slot++] = ind[i];
        }
    }
}

// ---------------------------------------------------------------------------
// Kernel 2 (R10): feature MLP, 16 points/block in 4 pipelined groups of 4.
// feat_kernel was the top dispatch (132.6us) with MfmaUtil 8% / VALUBusy 36%
// / occ 42% => latency/overhead-bound: per-block setup (build_b, pos consts),
// stage-D weight reloads, and unhidden stage-A gather chains dominated at
// 8192 tiny blocks. Fix: PTS=16 per block (grid 2048) amortizes setup and
// stage-D weight loads 4x; group g+1's global gathers are issued into
// REGISTERS before group g's MFMA stages (async-stage split) and written to
// T0 after the post-B barrier, hiding gather latency under compute for 3 of
// 4 groups. 2 barriers/group (9/16pts vs 12). Arithmetic bit-identical.
// LDS = T0+T1+sm[16][64] ~38.8KB -> still 4 blocks/CU.
// ---------------------------------------------------------------------------
#define PTS 16     // points per block
#define NG  4      // groups of 4 points

__device__ __forceinline__ unsigned int packhl(float f) {
    const unsigned int u = __float_as_uint(f);
    const unsigned int h = u & 0xffff0000u;
    const float lf = f - __uint_as_float(h);
    return h | (__float_as_uint(lf) >> 16);
}

__device__ __forceinline__ void build_b(const float* __restrict__ wrow,
                                        bf16x8* hi, bf16x8* lo) {
    union { unsigned int u[4]; bf16x8 v; } H, L;
    #pragma unroll
    for (int r = 0; r < 4; ++r) {
        const float f0 = wrow[2 * r], f1 = wrow[2 * r + 1];
        const unsigned int h0 = __float_as_uint(f0) & 0xffff0000u;
        const unsigned int h1 = __float_as_uint(f1) & 0xffff0000u;
        const float l0 = f0 - __uint_as_float(h0);
        const float l1 = f1 - __uint_as_float(h1);
        H.u[r] = h1 | (h0 >> 16);
        L.u[r] = (__float_as_uint(l1) & 0xffff0000u) | (__float_as_uint(l0) >> 16);
    }
    *hi = H.v; *lo = L.v;
}

__device__ __forceinline__ void unpack_a(const unsigned int* __restrict__ Tu,
                                         bf16x8* hi, bf16x8* lo) {
    union { unsigned int u[4]; bf16x8 v; } H, L;
    #pragma unroll
    for (int r = 0; r < 4; ++r) {
        const unsigned int a = Tu[2 * r + 1], bb = Tu[2 * r];
        H.u[r] = __builtin_amdgcn_perm(a, bb, 0x07060302u);  // [a.hi16 : b.hi16]
        L.u[r] = __builtin_amdgcn_perm(a, bb, 0x05040100u);  // [a.lo16 : b.lo16]
    }
    *hi = H.v; *lo = L.v;
}

__device__ __forceinline__ f32x4 mfma3(f32x4 acc, bf16x8 ah, bf16x8 al,
                                       bf16x8 bh, bf16x8 bl) {
    acc = __builtin_amdgcn_mfma_f32_16x16x32_bf16(ah, bl, acc, 0, 0, 0);
    acc = __builtin_amdgcn_mfma_f32_16x16x32_bf16(al, bh, acc, 0, 0, 0);
    acc = __builtin_amdgcn_mfma_f32_16x16x32_bf16(ah, bh, acc, 0, 0, 0);
    return acc;
}

__global__ __launch_bounds__(256, 4) void feat_kernel(
    const float* __restrict__ pc1, const float* __restrict__ pc2,
    const float* __restrict__ feat1, const float* __restrict__ feat2,
    const float* __restrict__ pos_w, const float* __restrict__ pos_b,
    const float* __restrict__ w0, const float* __restrict__ b0,
    const float* __restrict__ w1, const float* __restrict__ b1,
    const float* __restrict__ t1w, const float* __restrict__ t1b,
    const float* __restrict__ t2w, const float* __restrict__ t2b,
    const int* __restrict__ knn, float* __restrict__ out)
{
    __shared__ unsigned int T0[4][16][68];    // 17.4 KB packed activations
    __shared__ unsigned int T1[4][16][68];    // 17.4 KB
    __shared__ float sm[PTS][64];             // 4 KB pooled features (16 pts)

    const int t    = threadIdx.x;
    const int w    = t >> 6;          // wave = N-tile index 0..3
    const int lane = t & 63;
    const int m    = lane & 15;       // A-row (neighbor) / C-col (channel)
    const int quad = lane >> 4;

    const int p0  = blockIdx.x * PTS;
    const int dir = p0 >> 14, bt = (p0 >> 13) & 1;
    const int n0  = p0 & (NPTS - 1);

    const float* __restrict__ pqd = dir ? pc2 : pc1;
    const float* __restrict__ pcd = dir ? pc1 : pc2;
    const float* __restrict__ fqd = dir ? feat2 : feat1;
    const float* __restrict__ fcd = dir ? feat1 : feat2;

    // ---- per-block setup (amortized over 16 points now) --------------------
    const int ocol = w * 16 + m;               // this lane's output channel
    bf16x8 Bh[2][2], Bl[2][2];                 // [layer][ktile]
    #pragma unroll
    for (int kt = 0; kt < 2; ++kt) {
        build_b(&w0[(size_t)ocol * 64 + kt * 32 + quad * 8], &Bh[0][kt], &Bl[0][kt]);
        build_b(&w1[(size_t)ocol * 64 + kt * 32 + quad * 8], &Bh[1][kt], &Bl[1][kt]);
    }
    const float bias1 = b0[ocol];
    const float bias2 = b1[ocol];

    const int cg0 = w * 16 + quad * 4;
    float pbc[4], pwx[4], pwy[4], pwz[4];
    #pragma unroll
    for (int i = 0; i < 4; ++i) {
        pbc[i] = pos_b[cg0 + i];
        pwx[i] = pos_w[(cg0 + i) * 3 + 0];
        pwy[i] = pos_w[(cg0 + i) * 3 + 1];
        pwz[i] = pos_w[(cg0 + i) * 3 + 2];
    }

    // ---- register staging for the pipelined gather -------------------------
    float  sdx[4], sdy[4], sdz[4];
    float4 sgf[4], sfq[4];

    auto loadg = [&](int gg) {      // issue group gg's gathers into registers
        #pragma unroll
        for (int pt = 0; pt < 4; ++pt) {
            const int pp = p0 + gg * 4 + pt;
            const int nn = n0 + gg * 4 + pt;
            const int id = knn[(size_t)pp * KNNK + m];
            const float* qp  = pqd + ((size_t)bt * NPTS + nn) * 3;
            const float* nbp = pcd + ((size_t)bt * NPTS + id) * 3;
            sdx[pt] = nbp[0] - qp[0];
            sdy[pt] = nbp[1] - qp[1];
            sdz[pt] = nbp[2] - qp[2];
            sgf[pt] = *(const float4*)&fcd[((size_t)bt * NPTS + id) * 64 + cg0];
            sfq[pt] = *(const float4*)&fqd[((size_t)bt * NPTS + nn) * 64 + cg0];
        }
    };

    auto storeg = [&]() {           // initial layer from staged regs -> T0
        #pragma unroll
        for (int pt = 0; pt < 4; ++pt) {
            const float gfa[4] = {sgf[pt].x, sgf[pt].y, sgf[pt].z, sgf[pt].w};
            const float fqa[4] = {sfq[pt].x, sfq[pt].y, sfq[pt].z, sfq[pt].w};
            uint4 U;
            unsigned int* Up = (unsigned int*)&U;
            #pragma unroll
            for (int i = 0; i < 4; ++i) {
                float v = gfa[i] + fqa[i] + pbc[i];
                v = fmaf(sdx[pt], pwx[i], v);
                v = fmaf(sdy[pt], pwy[i], v);
                v = fmaf(sdz[pt], pwz[i], v);
                v = fmaxf(v, LEAKY * v);
                Up[i] = packhl(v);
            }
            *(uint4*)&T0[pt][m][cg0] = U;
        }
    };

    // ---- prologue: group 0 -------------------------------------------------
    loadg(0);
    storeg();
    __syncthreads();

    // ---- pipelined group loop ----------------------------------------------
    #pragma unroll
    for (int g = 0; g < NG; ++g) {
        if (g + 1 < NG) loadg(g + 1);   // gathers hide under B(g)+C(g)

        // ---- stage B: layer 1 (MFMA) T0 -> T1 ------------------------------
        #pragma unroll
        for (int pt = 0; pt < 4; ++pt) {
            unsigned int Tu[8];
            bf16x8 Ah, Al;
            f32x4 acc = {0.f, 0.f, 0.f, 0.f};
            #pragma unroll
            for (int kt = 0; kt < 2; ++kt) {
                *(uint4*)&Tu[0] = *(const uint4*)&T0[pt][m][kt * 32 + quad * 8];
                *(uint4*)&Tu[4] = *(const uint4*)&T0[pt][m][kt * 32 + quad * 8 + 4];
                unpack_a(Tu, &Ah, &Al);
                acc = mfma3(acc, Ah, Al, Bh[0][kt], Bl[0][kt]);
            }
            #pragma unroll
            for (int r = 0; r < 4; ++r) {
                float v = acc[r] + bias1;
                v = fmaxf(v, LEAKY * v);
                T1[pt][quad * 4 + r][ocol] = packhl(v);
            }
        }
        __syncthreads();   // all waves done reading T0(g), T1(g) visible

        if (g + 1 < NG) storeg();       // overwrite T0 with group g+1

        // ---- stage C: layer 2 (MFMA) + max-pool -> sm ----------------------
        #pragma unroll
        for (int pt = 0; pt < 4; ++pt) {
            unsigned int Tu[8];
            bf16x8 Ah, Al;
            f32x4 acc = {0.f, 0.f, 0.f, 0.f};
            #pragma unroll
            for (int kt = 0; kt < 2; ++kt) {
                *(uint4*)&Tu[0] = *(const uint4*)&T1[pt][m][kt * 32 + quad * 8];
                *(uint4*)&Tu[4] = *(const uint4*)&T1[pt][m][kt * 32 + quad * 8 + 4];
                unpack_a(Tu, &Ah, &Al);
                acc = mfma3(acc, Ah, Al, Bh[1][kt], Bl[1][kt]);
            }
            float mx = -3.0e38f;
            #pragma unroll
            for (int r = 0; r < 4; ++r) {
                float v = acc[r] + bias2;
                v = fmaxf(v, LEAKY * v);
                mx = fmaxf(mx, v);
            }
            mx = fmaxf(mx, __shfl_xor(mx, 16));
            mx = fmaxf(mx, __shfl_xor(mx, 32));
            if (quad == 0) sm[g * 4 + pt][ocol] = mx;
        }
        __syncthreads();   // T0(g+1) ready for B(g+1); sm(g) visible
    }

    // ---- stage D: final 64->128 linear, 16 points, weights loaded once -----
    {
        const float* __restrict__ tw = dir ? t2w : t1w;
        const float* __restrict__ tb = dir ? t2b : t1b;
        const int o  = t & 127;
        const int pg = t >> 7;                 // 0..1: which pairs this thread owns
        float acc[8];
        const float bz = tb[o];
        #pragma unroll
        for (int i = 0; i < 8; ++i) acc[i] = bz;
        #pragma unroll
        for (int cc = 0; cc < 64; cc += 4) {
            const float4 wq = *(const float4*)&tw[(size_t)o * 64 + cc];
            #pragma unroll
            for (int pr = 0; pr < 4; ++pr) {
                const int pa = (2 * pr + pg) * 2;       // pair -> even point
                const float4 a0 = *(const float4*)&sm[pa][cc];
                const float4 a1 = *(const float4*)&sm[pa + 1][cc];
                float x0 = acc[2 * pr], x1 = acc[2 * pr + 1];
                x0 = fmaf(a0.x, wq.x, x0); x0 = fmaf(a0.y, wq.y, x0);
                x0 = fmaf(a0.z, wq.z, x0); x0 = fmaf(a0.w, wq.w, x0);
                x1 = fmaf(a1.x, wq.x, x1); x1 = fmaf(a1.y, wq.y, x1);
                x1 = fmaf(a1.z, wq.z, x1); x1 = fmaf(a1.w, wq.w, x1);
                acc[2 * pr] = x0; acc[2 * pr + 1] = x1;
            }
        }
        float* op = out + (size_t)dir * (2 * NPTS * 128);
        #pragma unroll
        for (int pr = 0; pr < 4; ++pr) {
            const int pa = (2 * pr + pg) * 2;
            op[((size_t)bt * NPTS + n0 + pa) * 128 + o]     = acc[2 * pr];
            op[((size_t)bt * NPTS + n0 + pa + 1) * 128 + o] = acc[2 * pr + 1];
        }
    }
}

// ---------------------------------------------------------------------------
extern "C" void kernel_launch(void* const* d_in, const int* in_sizes, int n_in,
                              void* d_out, int out_size, void* d_ws, size_t ws_size,
                              hipStream_t stream)
{
    const float* pc1   = (const float*)d_in[0];
    const float* pc2   = (const float*)d_in[1];
    const float* feat1 = (const float*)d_in[2];
    const float* feat2 = (const float*)d_in[3];
    const float* pos_w = (const float*)d_in[4];
    const float* pos_b = (const float*)d_in[5];
    const float* w0    = (const float*)d_in[6];
    const float* b0    = (const float*)d_in[7];
    const float* w1    = (const float*)d_in[8];
    const float* b1    = (const float*)d_in[9];
    const float* t1w   = (const float*)d_in[10];
    const float* t1b   = (const float*)d_in[11];
    const float* t2w   = (const float*)d_in[12];
    const float* t2b   = (const float*)d_in[13];

    int*   knn = (int*)d_ws;          // 32768 * 16 ints = 2 MB scratch
    float* out = (float*)d_out;

    hipLaunchKernelGGL(knn_kernel, dim3(32768 / QPB), dim3(KTH), 0, stream,
                       pc1, pc2, knn);
    hipLaunchKernelGGL(feat_kernel, dim3(32768 / PTS), dim3(256), 0, stream,
                       pc1, pc2, feat1, feat2, pos_w, pos_b,
                       w0, b0, w1, b1, t1w, t1b, t2w, t2b, knn, out);
}